// Round 21
// baseline (1823.107 us; speedup 1.0000x reference)
//
#include <hip/hip_runtime.h>

#define B_    8
#define N_    8192
#define M_    2000
#define K_    16
#define C1_   128
#define C2_   256
#define OUT_  100
#define SUBP_ 2048   // padded per-batch pitch for subsampled points (KNN2 candidates)
#define NCB_  248    // consumer blocks (grid 256 = 8 fps + 248 consumers, 1 block/CU)
#define PSTRIDE_ 32  // progress padding: 1 line (128B) per batch

// ---------------------------------------------------------------- R21: R20 + knn2/layer2 wave-level fusion
// R20 post-mortem: best 1794 (mega 1480 + knn2 70 + layer2 110 + pool 25 + gaps).
// knn2's wave already holds all layer2 inputs (own top-16 + f1 final after mega)
// -> fuse at wave level: knn_core->LDS (proven same-wave pattern), gather
// rel3+f1 rows into per-wave feat, run the identical pk-fma layer2 with t->lane.
// Kills one launch, the whole idx2 buffer (2MB w + 2MB r), and pipelines knn2
// VALU with layer2 memory phases across the block's 4 waves.

__device__ __forceinline__ unsigned long long umax64(unsigned long long a, unsigned long long b) {
    return a > b ? a : b;
}

template<int CTRL>
__device__ __forceinline__ unsigned long long dpp_max_u64(unsigned long long v) {
    int lo = __builtin_amdgcn_update_dpp(0, (int)(unsigned)(v & 0xFFFFFFFFull), CTRL, 0xF, 0xF, true);
    int hi = __builtin_amdgcn_update_dpp(0, (int)(v >> 32),                     CTRL, 0xF, 0xF, true);
    unsigned long long o = ((unsigned long long)(unsigned)hi << 32) | (unsigned)lo;
    return umax64(v, o);
}

template<int CTRL>
__device__ __forceinline__ float dpp_min_f32(float v) {
    int o = __builtin_amdgcn_update_dpp(__float_as_int(v), __float_as_int(v), CTRL, 0xF, 0xF, false);
    return fminf(v, __int_as_float(o));
}

__device__ __forceinline__ int spread3(int v) {   // 3 bits -> bits 0,3,6
    return (v & 1) | ((v & 2) << 2) | ((v & 4) << 4);
}

// ---------------------------------------------------------------- KNN core (proven): 1 wave per query, exact top-16 set
template<int NCH, int PITCH, bool TO_LDS>
__device__ __forceinline__ void knn_core(const float4* __restrict__ cand,
                                         float4 Q, int b, int base,
                                         int* __restrict__ outIdx, int* __restrict__ ldsIdx) {
    int lane = threadIdx.x & 63;
    const float4* Cb = cand + (size_t)b * PITCH;

    float v[16];
#pragma unroll
    for (int tt = 0; tt < 16; ++tt) v[tt] = 3.4e38f;

#pragma unroll 2
    for (int j = 0; j < NCH; ++j) {
        float4 c = Cb[j*64 + lane];
        float dot = fmaf(c.z, Q.z, fmaf(c.y, Q.y, c.x * Q.x));
        float d = fmaf(-2.0f, dot, Q.w + c.w);   // == (qq+ss) - 2*dot, single rounding
        v[15] = fminf(v[15], d);
#pragma unroll
        for (int tt = 15; tt >= 1; --tt) {       // restore sortedness: bubble toward 0
            float lo = fminf(v[tt-1], v[tt]);
            float hi = fmaxf(v[tt-1], v[tt]);
            v[tt-1] = lo; v[tt] = hi;
        }
    }

    float T = 0.0f;
    for (int r = 0; r < 16; ++r) {               // extract global min 16 times
        float g = v[0];
        g = dpp_min_f32<0x111>(g);
        g = dpp_min_f32<0x112>(g);
        g = dpp_min_f32<0x114>(g);
        g = dpp_min_f32<0x118>(g);
        g = dpp_min_f32<0x142>(g);
        g = dpp_min_f32<0x143>(g);
        g = __int_as_float(__builtin_amdgcn_readlane(__float_as_int(g), 63));  // wave-uniform
        unsigned long long mk = __ballot(v[0] == g);
        int fl = __ffsll(mk) - 1;
        if (lane == fl) {
#pragma unroll
            for (int tt = 0; tt < 15; ++tt) v[tt] = v[tt+1];
            v[15] = 3.4e38f;
        }
        T = g;
    }

    unsigned long long mlt = (1ull << lane) - 1ull;
    int cnt = 0;
    for (int j = 0; j < NCH; ++j) {              // all strictly-closer candidates
        float4 c = Cb[j*64 + lane];
        float dot = fmaf(c.z, Q.z, fmaf(c.y, Q.y, c.x * Q.x));
        float d = fmaf(-2.0f, dot, Q.w + c.w);
        bool lt = d < T;
        unsigned long long m1 = __ballot(lt);
        if (lt) {
            int slot = cnt + __popcll(m1 & mlt);
            if (TO_LDS) ldsIdx[slot] = j*64 + lane; else outIdx[base + slot] = j*64 + lane;
        }
        cnt += __popcll(m1);
    }
    int rem = K_ - cnt;                          // fill with earliest-index ties at T
    for (int j = 0; j < NCH && rem > 0; ++j) {
        float4 c = Cb[j*64 + lane];
        float dot = fmaf(c.z, Q.z, fmaf(c.y, Q.y, c.x * Q.x));
        float d = fmaf(-2.0f, dot, Q.w + c.w);
        bool eq = (d == T);
        unsigned long long m2 = __ballot(eq);
        int bef = __popcll(m2 & mlt);
        if (eq && bef < rem) {
            int slot = cnt + bef;
            if (TO_LDS) ldsIdx[slot] = j*64 + lane; else outIdx[base + slot] = j*64 + lane;
        }
        int take = __popcll(m2); if (take > rem) take = rem;
        cnt += take; rem -= take;
    }
}

// ---------------------------------------------------------------- mega kernel: fps producer + knn1/layer1 consumers
__global__ __launch_bounds__(512, 1) void mega_kernel(const float* __restrict__ x,
                                                      float4* __restrict__ coords4,
                                                      float4* __restrict__ sub4,
                                                      const float* __restrict__ W1,
                                                      const float* __restrict__ b1,
                                                      float* __restrict__ f1,
                                                      int* __restrict__ progress) {
    __shared__ float4 Clds[N_];                              // 128 KB (fps mirror)
    __shared__ unsigned short sidx[N_];                      // 16 KB  (fps sort map)
    __shared__ unsigned int hist[512];                       // 2 KB
    __shared__ __align__(16) unsigned long long wkey[2][8];
    __shared__ int plog[64];                                 // producer: pick-index ring
    __shared__ int   nbuf[8][K_];                            // consumer: per-wave top-16
    __shared__ float4 nghl[8][K_];                           // consumer: gathered neighbors

    int t = threadIdx.x;
    int w = t >> 6, lane = t & 63;

    if (blockIdx.x < B_) {
        // ================= FPS producer (v12 core; store-free steady loop) =================
        int b = blockIdx.x;
        const float* X = x + (size_t)b * N_ * 3;
        float4* C4 = coords4 + b * N_;

        if (t < 512) hist[t] = 0u;
        if (t < SUBP_ - M_)
            sub4[b*SUBP_ + M_ + t] = make_float4(1e15f, 1e15f, 1e15f, 3e30f);
        __syncthreads();

        int cellv[16];
#pragma unroll
        for (int j = 0; j < 16; ++j) {
            int i = t + j*512;
            float xx = X[i*3+0], yy = X[i*3+1], zz = X[i*3+2];
            float ss = fmaf(zz, zz, fmaf(yy, yy, xx*xx));
            float4 p = make_float4(xx, yy, zz, ss);
            C4[i] = p;
            Clds[i] = p;
            int cx = (int)(p.x * 8.0f); cx = cx < 0 ? 0 : (cx > 7 ? 7 : cx);
            int cy = (int)(p.y * 8.0f); cy = cy < 0 ? 0 : (cy > 7 ? 7 : cy);
            int cz = (int)(p.z * 8.0f); cz = cz < 0 ? 0 : (cz > 7 ? 7 : cz);
            int cell = (spread3(cx) << 2) | (spread3(cy) << 1) | spread3(cz);
            cellv[j] = cell;
            atomicAdd(&hist[cell], 1u);
        }
        __syncthreads();

        if (w == 0) {
            unsigned loc[8], tot = 0u;
#pragma unroll
            for (int c2 = 0; c2 < 8; ++c2) { loc[c2] = hist[lane*8 + c2]; tot += loc[c2]; }
            unsigned pre = tot;
#pragma unroll
            for (int d = 1; d < 64; d <<= 1) {
                unsigned o = __shfl_up(pre, d, 64);
                if (lane >= (unsigned)d) pre += o;
            }
            unsigned run = pre - tot;
#pragma unroll
            for (int c2 = 0; c2 < 8; ++c2) { unsigned v = loc[c2]; hist[lane*8 + c2] = run; run += v; }
        }
        __syncthreads();

#pragma unroll
        for (int j = 0; j < 16; ++j) {
            int i = t + j*512;
            unsigned pos = atomicAdd(&hist[cellv[j]], 1u);
            sidx[pos] = (unsigned short)i;
        }
        __syncthreads();

        int oct = (w < 4) ? w : 11 - w;
        int sbase = oct*1024 + lane*16;
        float px_[16], py_[16], pz_[16], mind[16];
        unsigned inv_[16];
        float wx0 =  1e30f, wy0 =  1e30f, wz0 =  1e30f;
        float wx1 = -1e30f, wy1 = -1e30f, wz1 = -1e30f;
#pragma unroll
        for (int j = 0; j < 16; ++j) {
            int o = (int)sidx[sbase + j];
            float4 p = Clds[o];
            px_[j] = p.x; py_[j] = p.y; pz_[j] = p.z;
            mind[j] = 1e30f;
            inv_[j] = 0xFFFFFFFFu - (unsigned)o;
            wx0 = fminf(wx0, p.x); wx1 = fmaxf(wx1, p.x);
            wy0 = fminf(wy0, p.y); wy1 = fmaxf(wy1, p.y);
            wz0 = fminf(wz0, p.z); wz1 = fmaxf(wz1, p.z);
        }
        for (int s = 1; s < 64; s <<= 1) {
            wx0 = fminf(wx0, __shfl_xor(wx0, s, 64)); wx1 = fmaxf(wx1, __shfl_xor(wx1, s, 64));
            wy0 = fminf(wy0, __shfl_xor(wy0, s, 64)); wy1 = fmaxf(wy1, __shfl_xor(wy1, s, 64));
            wz0 = fminf(wz0, __shfl_xor(wz0, s, 64)); wz1 = fmaxf(wz1, __shfl_xor(wz1, s, 64));
        }

        float4 P0 = Clds[0];
        if (t == 0) plog[0] = 0;                             // pick 0 logged (flushed at i=63)
        float Px = P0.x, Py = P0.y, Pz = P0.z;
        unsigned long long wk = ((unsigned long long)__float_as_uint(1e30f) << 32);
        float wmaxf = 1e30f;

        for (int i = 1; i < M_; ++i) {
            float qx = fminf(fmaxf(Px, wx0), wx1);
            float qy = fminf(fmaxf(Py, wy0), wy1);
            float qz = fminf(fmaxf(Pz, wz0), wz1);
            float ddx = Px - qx, ddy = Py - qy, ddz = Pz - qz;
            float dmin2 = fmaf(ddz, ddz, fmaf(ddy, ddy, ddx*ddx));
            if (dmin2 * 0.99999f < wmaxf) {
                float runmax = -3.4e38f;
                unsigned ib = 0u;
#pragma unroll
                for (int j = 0; j < 16; ++j) {
                    float dx = px_[j] - Px, dy = py_[j] - Py, dz = pz_[j] - Pz;
                    float d = fmaf(dz, dz, fmaf(dy, dy, dx*dx));
                    float m = fminf(mind[j], d);
                    mind[j] = m;
                    ib = (m > runmax) ? inv_[j] : ib;
                    runmax = fmaxf(runmax, m);
                }
                unsigned long long best = ((unsigned long long)__float_as_uint(runmax) << 32)
                                        | (unsigned long long)ib;
                best = dpp_max_u64<0x111>(best);
                best = dpp_max_u64<0x112>(best);
                best = dpp_max_u64<0x114>(best);
                best = dpp_max_u64<0x118>(best);
                best = dpp_max_u64<0x142>(best);
                best = dpp_max_u64<0x143>(best);
                wk = best;
                wmaxf = __uint_as_float((unsigned)__builtin_amdgcn_readlane((int)(unsigned)(wk >> 32), 63));
            }
            if (lane == 63) wkey[i & 1][w] = wk;
            __syncthreads();
            const ulonglong2* wk2 = (const ulonglong2*)wkey[i & 1];
            ulonglong2 q0 = wk2[0], q1 = wk2[1], q2 = wk2[2], q3 = wk2[3];
            unsigned long long gk = umax64(umax64(umax64(q0.x, q0.y), umax64(q1.x, q1.y)),
                                           umax64(umax64(q2.x, q2.y), umax64(q3.x, q3.y)));
            int last = (int)(0xFFFFFFFFu - (unsigned)(gk & 0xFFFFFFFFull));
            float4 P4 = Clds[last];
            Px = P4.x; Py = P4.y; Pz = P4.z;
            if (t == 0) plog[i & 63] = last;                 // LDS only: steady loop has NO global ops
            if ((i & 63) == 63) {                            // burst-flush 64 picks + publish
                if (w == 0) {                                // same-wave plog visibility (t0 wrote it)
                    int pick = i - 63 + lane;
                    sub4[b*SUBP_ + pick] = Clds[plog[pick & 63]];
                }
                if (t == 0)                                  // release: wave-level vmcnt drain orders flush
                    __hip_atomic_store(&progress[b*PSTRIDE_], i + 1, __ATOMIC_RELEASE, __HIP_MEMORY_SCOPE_AGENT);
            }
        }
        // tail: picks 1984..1999 (slots 0..15), then final publish
        if (w == 0 && lane < M_ - 1984) {
            int pick = 1984 + lane;
            sub4[b*SUBP_ + pick] = Clds[plog[pick & 63]];
        }
        if (t == 0)
            __hip_atomic_store(&progress[b*PSTRIDE_], M_, __ATOMIC_RELEASE, __HIP_MEMORY_SCOPE_AGENT);
    } else {
        // ================= consumers: wave w owns batch w; block cb owns m = cb+248k =================
        int cb = blockIdx.x - B_;                 // 0..247
        int bb = w;                               // batch = wave index (8 waves, 8 batches)
        float w0  = W1[lane],            w1  = W1[C1_ + lane],      w2  = W1[2*C1_ + lane];
        float w3  = W1[3*C1_ + lane],    w4  = W1[4*C1_ + lane],    w5  = W1[5*C1_ + lane];
        float w0b = W1[lane+64],         w1b = W1[C1_ + lane+64],   w2b = W1[2*C1_ + lane+64];
        float w3b = W1[3*C1_ + lane+64], w4b = W1[4*C1_ + lane+64], w5b = W1[5*C1_ + lane+64];
        float bias = b1[lane], biasb = b1[lane+64];

        for (int m = cb; m < M_; m += NCB_) {
            // RELAXED spin (no per-poll invalidate) + ONE acquire fence after exit
            while (__hip_atomic_load(&progress[bb*PSTRIDE_], __ATOMIC_RELAXED, __HIP_MEMORY_SCOPE_AGENT) < m + 1)
                __builtin_amdgcn_s_sleep(127);
            __builtin_amdgcn_fence(__ATOMIC_ACQUIRE, "agent");
            float4 Q = sub4[bb*SUBP_ + m];
            knn_core<N_/64, N_, true>(coords4, Q, bb, 0, nullptr, nbuf[w]);
            if (lane < K_) nghl[w][lane] = coords4[(size_t)bb*N_ + nbuf[w][lane]];
            // same-wave LDS write->read: in-order per wave, no barrier needed
            float mxa = -3.4e38f, mxb = -3.4e38f;
#pragma unroll
            for (int k = 0; k < K_; ++k) {
                float4 n = nghl[w][k];
                float rx = n.x - Q.x, ry = n.y - Q.y, rz = n.z - Q.z;
                float s = rx*w0; s = fmaf(ry,w1,s); s = fmaf(rz,w2,s);
                s = fmaf(n.x,w3,s); s = fmaf(n.y,w4,s); s = fmaf(n.z,w5,s);
                s += bias; s = fmaxf(s, 0.0f); mxa = fmaxf(mxa, s);
                float sb = rx*w0b; sb = fmaf(ry,w1b,sb); sb = fmaf(rz,w2b,sb);
                sb = fmaf(n.x,w3b,sb); sb = fmaf(n.y,w4b,sb); sb = fmaf(n.z,w5b,sb);
                sb += biasb; sb = fmaxf(sb, 0.0f); mxb = fmaxf(mxb, sb);
            }
            int q = bb*M_ + m;
            f1[q*C1_ + lane]      = mxa;
            f1[q*C1_ + lane + 64] = mxb;
        }
        // done: knn2+layer2 run fused, full width, after mega
    }
}

// ---------------------------------------------------------------- zero progress (per replay)
__global__ void zero_kernel(int* __restrict__ p) {
    if (threadIdx.x < B_*PSTRIDE_) p[threadIdx.x] = 0;
}

// ---------------------------------------------------------------- fused knn2 + layer2: 1 wave per query, no barriers
// Wave computes its query's knn2 top-16 into LDS (proven same-wave pattern),
// gathers rel3 + f1 rows into its private feat region, then runs the identical
// pk-fma layer2 (lane owns 4 channels). f1 is complete (mega finished).
#define FPAD 20
typedef float v2f __attribute__((ext_vector_type(2)));
__global__ __launch_bounds__(256) void knn2l2_kernel(const float4* __restrict__ sub4,
        const float* __restrict__ f1,
        const float* __restrict__ W2, const float* __restrict__ b2,
        float* __restrict__ f2) {
    __shared__ __align__(16) float feat[4][(3 + C1_) * FPAD];   // 10.48 KB per wave
    __shared__ int nbuf[4][K_];
    int w = threadIdx.x >> 6, lane = threadIdx.x & 63;
    int q = blockIdx.x * 4 + w;
    int b = q / M_, m = q % M_;
    float4 Q = sub4[b*SUBP_ + m];

    knn_core<SUBP_/64, SUBP_, true>(sub4, Q, b, 0, nullptr, nbuf[w]);

    float* fw = feat[w];
    if (lane < K_) {                              // rel3 rows (same-wave visibility of nbuf)
        int ik = nbuf[w][lane];
        float4 n = sub4[b*SUBP_ + ik];
        fw[0*FPAD + lane] = n.x - Q.x;
        fw[1*FPAD + lane] = n.y - Q.y;
        fw[2*FPAD + lane] = n.z - Q.z;
    }
    for (int e = lane; e < K_ * C1_; e += 64) {   // stage gathered f1 rows: feat[3+cc][k]
        int k = e >> 7, cc = e & 127;
        fw[(3 + cc)*FPAD + k] = f1[(b*M_ + nbuf[w][k])*C1_ + cc];
    }
    // all staging writes are same-wave; compiler inserts lgkmcnt before reads

    v2f acc2[K_][2];
#pragma unroll
    for (int k = 0; k < K_; ++k) { acc2[k][0] = (v2f){0.f,0.f}; acc2[k][1] = (v2f){0.f,0.f}; }
    int c0 = lane * 4;                            // 4 channels per lane, 64 lanes = 256 ch
    for (int f = 0; f < 3 + C1_; ++f) {
        float4 wv = *(const float4*)(W2 + f*C2_ + c0);
        v2f w01 = (v2f){wv.x, wv.y}, w23 = (v2f){wv.z, wv.w};
        const float* row = fw + f*FPAD;
        float4 g0 = *(const float4*)(row + 0);
        float4 g1 = *(const float4*)(row + 4);
        float4 g2 = *(const float4*)(row + 8);
        float4 g3 = *(const float4*)(row + 12);
        float gk[16] = {g0.x,g0.y,g0.z,g0.w, g1.x,g1.y,g1.z,g1.w,
                        g2.x,g2.y,g2.z,g2.w, g3.x,g3.y,g3.z,g3.w};
#pragma unroll
        for (int k = 0; k < K_; ++k) {
            v2f gg = (v2f){gk[k], gk[k]};         // splat -> op_sel broadcast in v_pk_fma_f32
            acc2[k][0] = __builtin_elementwise_fma(gg, w01, acc2[k][0]);
            acc2[k][1] = __builtin_elementwise_fma(gg, w23, acc2[k][1]);
        }
    }
    float4 bb = *(const float4*)(b2 + c0);
    float mx0 = -3.4e38f, mx1 = -3.4e38f, mx2 = -3.4e38f, mx3 = -3.4e38f;
#pragma unroll
    for (int k = 0; k < K_; ++k) {
        float h0 = fmaxf(acc2[k][0].x + bb.x, 0.0f);
        float h1 = fmaxf(acc2[k][0].y + bb.y, 0.0f);
        float h2 = fmaxf(acc2[k][1].x + bb.z, 0.0f);
        float h3 = fmaxf(acc2[k][1].y + bb.w, 0.0f);
        mx0 = fmaxf(mx0, h0); mx1 = fmaxf(mx1, h1);
        mx2 = fmaxf(mx2, h2); mx3 = fmaxf(mx3, h3);
    }
    *(float4*)(f2 + q*C2_ + c0) = make_float4(mx0, mx1, mx2, mx3);
}

// ---------------------------------------------------------------- fused adaptive max+avg pool
__global__ __launch_bounds__(256) void pool_kernel(const float* __restrict__ f2,
                                                   float* __restrict__ out) {
    int bo = blockIdx.x;
    int b = bo / OUT_, o = bo % OUT_;
    int c = threadIdx.x;
    float mx = -3.4e38f, sm = 0.0f;
#pragma unroll
    for (int w = 0; w < M_/OUT_; ++w) {
        float v = f2[(b*M_ + o*(M_/OUT_) + w)*C2_ + c];
        mx = fmaxf(mx, v);
        sm += v;
    }
    out[(b*C2_ + c)*OUT_ + o] = mx + sm / (float)(M_/OUT_);
}

// ---------------------------------------------------------------- launch
extern "C" void kernel_launch(void* const* d_in, const int* in_sizes, int n_in,
                              void* d_out, int out_size, void* d_ws, size_t ws_size,
                              hipStream_t stream) {
    const float* x  = (const float*)d_in[0];
    const float* W1 = (const float*)d_in[1];
    const float* b1 = (const float*)d_in[2];
    const float* W2 = (const float*)d_in[3];
    const float* b2 = (const float*)d_in[4];
    float* out = (float*)d_out;

    char* ws = (char*)d_ws;
    size_t off = 0;
    auto alloc = [&](size_t bytes) {
        void* p = ws + off;
        off += (bytes + 255) & ~(size_t)255;
        return p;
    };
    float4* coords4 = (float4*)alloc((size_t)B_*N_*sizeof(float4));     // 2 MB
    float4* sub4    = (float4*)alloc((size_t)B_*SUBP_*sizeof(float4));  // 256 KB
    float*  f1      = (float*)alloc((size_t)B_*M_*C1_*sizeof(float));   // 8 MB
    float*  f2      = (float*)alloc((size_t)B_*M_*C2_*sizeof(float));   // 16 MB
    int*    progress= (int*)  alloc((size_t)B_*PSTRIDE_*sizeof(int));

    zero_kernel<<<1, 256, 0, stream>>>(progress);
    mega_kernel<<<B_ + NCB_, 512, 0, stream>>>(x, coords4, sub4, W1, b1, f1, progress);
    knn2l2_kernel<<<B_*M_/4, 256, 0, stream>>>(sub4, f1, W2, b2, f2);
    pool_kernel<<<B_*OUT_, 256, 0, stream>>>(f2, out);
}

// Round 22
// 1787.988 us; speedup vs baseline: 1.0196x; 1.0196x over previous
//
#include <hip/hip_runtime.h>

#define B_    8
#define N_    8192
#define M_    2000
#define K_    16
#define C1_   128
#define C2_   256
#define OUT_  100
#define SUBP_ 2048   // padded per-batch pitch for subsampled points (KNN2 candidates)
#define NCB_  248    // consumer blocks (grid 256 = 8 fps + 248 consumers, 1 block/CU)
#define PSTRIDE_ 32  // progress padding: 1 line (128B) per batch

// ---------------------------------------------------------------- R22 = R20 locked (session best: 1794us)
// R21 post-mortem: knn2+layer2 fusion regressed (+29us) — combined VGPR footprint
// cut occupancy where layer2's gather latency needs TLP; separate kernels let each
// phase run at its own optimal width. Final configuration:
//   mega   = fps producer (store-free loop, 64-pick burst flush, release publish)
//            + 248 consumer blocks overlapping knn1+layer1 under fps
//            (relaxed polls + per-query acquire fence)
//   knn2   = standalone full-width (16000 waves)
//   layer2 = standalone (pk-fma), pool = standalone

__device__ __forceinline__ unsigned long long umax64(unsigned long long a, unsigned long long b) {
    return a > b ? a : b;
}

template<int CTRL>
__device__ __forceinline__ unsigned long long dpp_max_u64(unsigned long long v) {
    int lo = __builtin_amdgcn_update_dpp(0, (int)(unsigned)(v & 0xFFFFFFFFull), CTRL, 0xF, 0xF, true);
    int hi = __builtin_amdgcn_update_dpp(0, (int)(v >> 32),                     CTRL, 0xF, 0xF, true);
    unsigned long long o = ((unsigned long long)(unsigned)hi << 32) | (unsigned)lo;
    return umax64(v, o);
}

template<int CTRL>
__device__ __forceinline__ float dpp_min_f32(float v) {
    int o = __builtin_amdgcn_update_dpp(__float_as_int(v), __float_as_int(v), CTRL, 0xF, 0xF, false);
    return fminf(v, __int_as_float(o));
}

__device__ __forceinline__ int spread3(int v) {   // 3 bits -> bits 0,3,6
    return (v & 1) | ((v & 2) << 2) | ((v & 4) << 4);
}

// ---------------------------------------------------------------- KNN core (proven): 1 wave per query, exact top-16 set
template<int NCH, int PITCH, bool TO_LDS>
__device__ __forceinline__ void knn_core(const float4* __restrict__ cand,
                                         float4 Q, int b, int base,
                                         int* __restrict__ outIdx, int* __restrict__ ldsIdx) {
    int lane = threadIdx.x & 63;
    const float4* Cb = cand + (size_t)b * PITCH;

    float v[16];
#pragma unroll
    for (int tt = 0; tt < 16; ++tt) v[tt] = 3.4e38f;

#pragma unroll 2
    for (int j = 0; j < NCH; ++j) {
        float4 c = Cb[j*64 + lane];
        float dot = fmaf(c.z, Q.z, fmaf(c.y, Q.y, c.x * Q.x));
        float d = fmaf(-2.0f, dot, Q.w + c.w);   // == (qq+ss) - 2*dot, single rounding
        v[15] = fminf(v[15], d);
#pragma unroll
        for (int tt = 15; tt >= 1; --tt) {       // restore sortedness: bubble toward 0
            float lo = fminf(v[tt-1], v[tt]);
            float hi = fmaxf(v[tt-1], v[tt]);
            v[tt-1] = lo; v[tt] = hi;
        }
    }

    float T = 0.0f;
    for (int r = 0; r < 16; ++r) {               // extract global min 16 times
        float g = v[0];
        g = dpp_min_f32<0x111>(g);
        g = dpp_min_f32<0x112>(g);
        g = dpp_min_f32<0x114>(g);
        g = dpp_min_f32<0x118>(g);
        g = dpp_min_f32<0x142>(g);
        g = dpp_min_f32<0x143>(g);
        g = __int_as_float(__builtin_amdgcn_readlane(__float_as_int(g), 63));  // wave-uniform
        unsigned long long mk = __ballot(v[0] == g);
        int fl = __ffsll(mk) - 1;
        if (lane == fl) {
#pragma unroll
            for (int tt = 0; tt < 15; ++tt) v[tt] = v[tt+1];
            v[15] = 3.4e38f;
        }
        T = g;
    }

    unsigned long long mlt = (1ull << lane) - 1ull;
    int cnt = 0;
    for (int j = 0; j < NCH; ++j) {              // all strictly-closer candidates
        float4 c = Cb[j*64 + lane];
        float dot = fmaf(c.z, Q.z, fmaf(c.y, Q.y, c.x * Q.x));
        float d = fmaf(-2.0f, dot, Q.w + c.w);
        bool lt = d < T;
        unsigned long long m1 = __ballot(lt);
        if (lt) {
            int slot = cnt + __popcll(m1 & mlt);
            if (TO_LDS) ldsIdx[slot] = j*64 + lane; else outIdx[base + slot] = j*64 + lane;
        }
        cnt += __popcll(m1);
    }
    int rem = K_ - cnt;                          // fill with earliest-index ties at T
    for (int j = 0; j < NCH && rem > 0; ++j) {
        float4 c = Cb[j*64 + lane];
        float dot = fmaf(c.z, Q.z, fmaf(c.y, Q.y, c.x * Q.x));
        float d = fmaf(-2.0f, dot, Q.w + c.w);
        bool eq = (d == T);
        unsigned long long m2 = __ballot(eq);
        int bef = __popcll(m2 & mlt);
        if (eq && bef < rem) {
            int slot = cnt + bef;
            if (TO_LDS) ldsIdx[slot] = j*64 + lane; else outIdx[base + slot] = j*64 + lane;
        }
        int take = __popcll(m2); if (take > rem) take = rem;
        cnt += take; rem -= take;
    }
}

// ---------------------------------------------------------------- mega kernel: fps producer + knn1/layer1 consumers
__global__ __launch_bounds__(512, 1) void mega_kernel(const float* __restrict__ x,
                                                      float4* __restrict__ coords4,
                                                      float4* __restrict__ sub4,
                                                      const float* __restrict__ W1,
                                                      const float* __restrict__ b1,
                                                      float* __restrict__ f1,
                                                      int* __restrict__ progress) {
    __shared__ float4 Clds[N_];                              // 128 KB (fps mirror)
    __shared__ unsigned short sidx[N_];                      // 16 KB  (fps sort map)
    __shared__ unsigned int hist[512];                       // 2 KB
    __shared__ __align__(16) unsigned long long wkey[2][8];
    __shared__ int plog[64];                                 // producer: pick-index ring
    __shared__ int   nbuf[8][K_];                            // consumer: per-wave top-16
    __shared__ float4 nghl[8][K_];                           // consumer: gathered neighbors

    int t = threadIdx.x;
    int w = t >> 6, lane = t & 63;

    if (blockIdx.x < B_) {
        // ================= FPS producer (v12 core; store-free steady loop) =================
        int b = blockIdx.x;
        const float* X = x + (size_t)b * N_ * 3;
        float4* C4 = coords4 + b * N_;

        if (t < 512) hist[t] = 0u;
        if (t < SUBP_ - M_)
            sub4[b*SUBP_ + M_ + t] = make_float4(1e15f, 1e15f, 1e15f, 3e30f);
        __syncthreads();

        int cellv[16];
#pragma unroll
        for (int j = 0; j < 16; ++j) {
            int i = t + j*512;
            float xx = X[i*3+0], yy = X[i*3+1], zz = X[i*3+2];
            float ss = fmaf(zz, zz, fmaf(yy, yy, xx*xx));
            float4 p = make_float4(xx, yy, zz, ss);
            C4[i] = p;
            Clds[i] = p;
            int cx = (int)(p.x * 8.0f); cx = cx < 0 ? 0 : (cx > 7 ? 7 : cx);
            int cy = (int)(p.y * 8.0f); cy = cy < 0 ? 0 : (cy > 7 ? 7 : cy);
            int cz = (int)(p.z * 8.0f); cz = cz < 0 ? 0 : (cz > 7 ? 7 : cz);
            int cell = (spread3(cx) << 2) | (spread3(cy) << 1) | spread3(cz);
            cellv[j] = cell;
            atomicAdd(&hist[cell], 1u);
        }
        __syncthreads();

        if (w == 0) {
            unsigned loc[8], tot = 0u;
#pragma unroll
            for (int c2 = 0; c2 < 8; ++c2) { loc[c2] = hist[lane*8 + c2]; tot += loc[c2]; }
            unsigned pre = tot;
#pragma unroll
            for (int d = 1; d < 64; d <<= 1) {
                unsigned o = __shfl_up(pre, d, 64);
                if (lane >= (unsigned)d) pre += o;
            }
            unsigned run = pre - tot;
#pragma unroll
            for (int c2 = 0; c2 < 8; ++c2) { unsigned v = loc[c2]; hist[lane*8 + c2] = run; run += v; }
        }
        __syncthreads();

#pragma unroll
        for (int j = 0; j < 16; ++j) {
            int i = t + j*512;
            unsigned pos = atomicAdd(&hist[cellv[j]], 1u);
            sidx[pos] = (unsigned short)i;
        }
        __syncthreads();

        int oct = (w < 4) ? w : 11 - w;
        int sbase = oct*1024 + lane*16;
        float px_[16], py_[16], pz_[16], mind[16];
        unsigned inv_[16];
        float wx0 =  1e30f, wy0 =  1e30f, wz0 =  1e30f;
        float wx1 = -1e30f, wy1 = -1e30f, wz1 = -1e30f;
#pragma unroll
        for (int j = 0; j < 16; ++j) {
            int o = (int)sidx[sbase + j];
            float4 p = Clds[o];
            px_[j] = p.x; py_[j] = p.y; pz_[j] = p.z;
            mind[j] = 1e30f;
            inv_[j] = 0xFFFFFFFFu - (unsigned)o;
            wx0 = fminf(wx0, p.x); wx1 = fmaxf(wx1, p.x);
            wy0 = fminf(wy0, p.y); wy1 = fmaxf(wy1, p.y);
            wz0 = fminf(wz0, p.z); wz1 = fmaxf(wz1, p.z);
        }
        for (int s = 1; s < 64; s <<= 1) {
            wx0 = fminf(wx0, __shfl_xor(wx0, s, 64)); wx1 = fmaxf(wx1, __shfl_xor(wx1, s, 64));
            wy0 = fminf(wy0, __shfl_xor(wy0, s, 64)); wy1 = fmaxf(wy1, __shfl_xor(wy1, s, 64));
            wz0 = fminf(wz0, __shfl_xor(wz0, s, 64)); wz1 = fmaxf(wz1, __shfl_xor(wz1, s, 64));
        }

        float4 P0 = Clds[0];
        if (t == 0) plog[0] = 0;                             // pick 0 logged (flushed at i=63)
        float Px = P0.x, Py = P0.y, Pz = P0.z;
        unsigned long long wk = ((unsigned long long)__float_as_uint(1e30f) << 32);
        float wmaxf = 1e30f;

        for (int i = 1; i < M_; ++i) {
            float qx = fminf(fmaxf(Px, wx0), wx1);
            float qy = fminf(fmaxf(Py, wy0), wy1);
            float qz = fminf(fmaxf(Pz, wz0), wz1);
            float ddx = Px - qx, ddy = Py - qy, ddz = Pz - qz;
            float dmin2 = fmaf(ddz, ddz, fmaf(ddy, ddy, ddx*ddx));
            if (dmin2 * 0.99999f < wmaxf) {
                float runmax = -3.4e38f;
                unsigned ib = 0u;
#pragma unroll
                for (int j = 0; j < 16; ++j) {
                    float dx = px_[j] - Px, dy = py_[j] - Py, dz = pz_[j] - Pz;
                    float d = fmaf(dz, dz, fmaf(dy, dy, dx*dx));
                    float m = fminf(mind[j], d);
                    mind[j] = m;
                    ib = (m > runmax) ? inv_[j] : ib;
                    runmax = fmaxf(runmax, m);
                }
                unsigned long long best = ((unsigned long long)__float_as_uint(runmax) << 32)
                                        | (unsigned long long)ib;
                best = dpp_max_u64<0x111>(best);
                best = dpp_max_u64<0x112>(best);
                best = dpp_max_u64<0x114>(best);
                best = dpp_max_u64<0x118>(best);
                best = dpp_max_u64<0x142>(best);
                best = dpp_max_u64<0x143>(best);
                wk = best;
                wmaxf = __uint_as_float((unsigned)__builtin_amdgcn_readlane((int)(unsigned)(wk >> 32), 63));
            }
            if (lane == 63) wkey[i & 1][w] = wk;
            __syncthreads();
            const ulonglong2* wk2 = (const ulonglong2*)wkey[i & 1];
            ulonglong2 q0 = wk2[0], q1 = wk2[1], q2 = wk2[2], q3 = wk2[3];
            unsigned long long gk = umax64(umax64(umax64(q0.x, q0.y), umax64(q1.x, q1.y)),
                                           umax64(umax64(q2.x, q2.y), umax64(q3.x, q3.y)));
            int last = (int)(0xFFFFFFFFu - (unsigned)(gk & 0xFFFFFFFFull));
            float4 P4 = Clds[last];
            Px = P4.x; Py = P4.y; Pz = P4.z;
            if (t == 0) plog[i & 63] = last;                 // LDS only: steady loop has NO global ops
            if ((i & 63) == 63) {                            // burst-flush 64 picks + publish
                if (w == 0) {                                // same-wave plog visibility (t0 wrote it)
                    int pick = i - 63 + lane;
                    sub4[b*SUBP_ + pick] = Clds[plog[pick & 63]];
                }
                if (t == 0)                                  // release: wave-level vmcnt drain orders flush
                    __hip_atomic_store(&progress[b*PSTRIDE_], i + 1, __ATOMIC_RELEASE, __HIP_MEMORY_SCOPE_AGENT);
            }
        }
        // tail: picks 1984..1999 (slots 0..15), then final publish
        if (w == 0 && lane < M_ - 1984) {
            int pick = 1984 + lane;
            sub4[b*SUBP_ + pick] = Clds[plog[pick & 63]];
        }
        if (t == 0)
            __hip_atomic_store(&progress[b*PSTRIDE_], M_, __ATOMIC_RELEASE, __HIP_MEMORY_SCOPE_AGENT);
    } else {
        // ================= consumers: wave w owns batch w; block cb owns m = cb+248k =================
        int cb = blockIdx.x - B_;                 // 0..247
        int bb = w;                               // batch = wave index (8 waves, 8 batches)
        float w0  = W1[lane],            w1  = W1[C1_ + lane],      w2  = W1[2*C1_ + lane];
        float w3  = W1[3*C1_ + lane],    w4  = W1[4*C1_ + lane],    w5  = W1[5*C1_ + lane];
        float w0b = W1[lane+64],         w1b = W1[C1_ + lane+64],   w2b = W1[2*C1_ + lane+64];
        float w3b = W1[3*C1_ + lane+64], w4b = W1[4*C1_ + lane+64], w5b = W1[5*C1_ + lane+64];
        float bias = b1[lane], biasb = b1[lane+64];

        for (int m = cb; m < M_; m += NCB_) {
            // RELAXED spin (no per-poll invalidate) + ONE acquire fence after exit
            while (__hip_atomic_load(&progress[bb*PSTRIDE_], __ATOMIC_RELAXED, __HIP_MEMORY_SCOPE_AGENT) < m + 1)
                __builtin_amdgcn_s_sleep(127);
            __builtin_amdgcn_fence(__ATOMIC_ACQUIRE, "agent");
            float4 Q = sub4[bb*SUBP_ + m];
            knn_core<N_/64, N_, true>(coords4, Q, bb, 0, nullptr, nbuf[w]);
            if (lane < K_) nghl[w][lane] = coords4[(size_t)bb*N_ + nbuf[w][lane]];
            // same-wave LDS write->read: in-order per wave, no barrier needed
            float mxa = -3.4e38f, mxb = -3.4e38f;
#pragma unroll
            for (int k = 0; k < K_; ++k) {
                float4 n = nghl[w][k];
                float rx = n.x - Q.x, ry = n.y - Q.y, rz = n.z - Q.z;
                float s = rx*w0; s = fmaf(ry,w1,s); s = fmaf(rz,w2,s);
                s = fmaf(n.x,w3,s); s = fmaf(n.y,w4,s); s = fmaf(n.z,w5,s);
                s += bias; s = fmaxf(s, 0.0f); mxa = fmaxf(mxa, s);
                float sb = rx*w0b; sb = fmaf(ry,w1b,sb); sb = fmaf(rz,w2b,sb);
                sb = fmaf(n.x,w3b,sb); sb = fmaf(n.y,w4b,sb); sb = fmaf(n.z,w5b,sb);
                sb += biasb; sb = fmaxf(sb, 0.0f); mxb = fmaxf(mxb, sb);
            }
            int q = bb*M_ + m;
            f1[q*C1_ + lane]      = mxa;
            f1[q*C1_ + lane + 64] = mxb;
        }
        // done: knn2 runs as a standalone full-width kernel after mega
    }
}

// ---------------------------------------------------------------- knn2 standalone (full 16000-wave width)
__global__ __launch_bounds__(256) void knn2_kernel(const float4* __restrict__ sub4,
                                                   int* __restrict__ idx2) {
    int q = blockIdx.x * 4 + (threadIdx.x >> 6);
    int b = q / M_, m = q % M_;
    float4 Q = sub4[b * SUBP_ + m];
    knn_core<SUBP_/64, SUBP_, false>(sub4, Q, b, q*K_, idx2, nullptr);
}

// ---------------------------------------------------------------- zero progress (per replay)
__global__ void zero_kernel(int* __restrict__ p) {
    if (threadIdx.x < B_*PSTRIDE_) p[threadIdx.x] = 0;
}

// ---------------------------------------------------------------- layer 2: feats=[rel(3), fg(128)] x W2[131,256], relu, max over k
#define FPAD 20
typedef float v2f __attribute__((ext_vector_type(2)));
__global__ __launch_bounds__(64) void layer2_kernel(const float4* __restrict__ sub4,
        const float* __restrict__ f1, const int* __restrict__ idx2,
        const float* __restrict__ W2, const float* __restrict__ b2,
        float* __restrict__ f2) {
    int q = blockIdx.x;
    int b = q / M_, m = q % M_;
    int t = threadIdx.x;
    __shared__ __align__(16) float feat[(3 + C1_) * FPAD];
    __shared__ int nidx[K_];
    float4 Q = sub4[b*SUBP_ + m];
    if (t < K_) {
        int ik = idx2[q*K_ + t];
        nidx[t] = ik;
        float4 n = sub4[b*SUBP_ + ik];
        feat[0*FPAD + t] = n.x - Q.x;
        feat[1*FPAD + t] = n.y - Q.y;
        feat[2*FPAD + t] = n.z - Q.z;
    }
    __syncthreads();
    for (int e = t; e < K_ * C1_; e += 64) {
        int k = e >> 7, cc = e & 127;
        feat[(3 + cc)*FPAD + k] = f1[(b*M_ + nidx[k])*C1_ + cc];
    }
    __syncthreads();

    v2f acc2[K_][2];
#pragma unroll
    for (int k = 0; k < K_; ++k) { acc2[k][0] = (v2f){0.f,0.f}; acc2[k][1] = (v2f){0.f,0.f}; }
    int c0 = t * 4;
    for (int f = 0; f < 3 + C1_; ++f) {
        float4 wv = *(const float4*)(W2 + f*C2_ + c0);
        v2f w01 = (v2f){wv.x, wv.y}, w23 = (v2f){wv.z, wv.w};
        const float* row = feat + f*FPAD;
        float4 g0 = *(const float4*)(row + 0);
        float4 g1 = *(const float4*)(row + 4);
        float4 g2 = *(const float4*)(row + 8);
        float4 g3 = *(const float4*)(row + 12);
        float gk[16] = {g0.x,g0.y,g0.z,g0.w, g1.x,g1.y,g1.z,g1.w,
                        g2.x,g2.y,g2.z,g2.w, g3.x,g3.y,g3.z,g3.w};
#pragma unroll
        for (int k = 0; k < K_; ++k) {
            v2f gg = (v2f){gk[k], gk[k]};
            acc2[k][0] = __builtin_elementwise_fma(gg, w01, acc2[k][0]);
            acc2[k][1] = __builtin_elementwise_fma(gg, w23, acc2[k][1]);
        }
    }
    float4 bb = *(const float4*)(b2 + c0);
    float mx0 = -3.4e38f, mx1 = -3.4e38f, mx2 = -3.4e38f, mx3 = -3.4e38f;
#pragma unroll
    for (int k = 0; k < K_; ++k) {
        float h0 = fmaxf(acc2[k][0].x + bb.x, 0.0f);
        float h1 = fmaxf(acc2[k][0].y + bb.y, 0.0f);
        float h2 = fmaxf(acc2[k][1].x + bb.z, 0.0f);
        float h3 = fmaxf(acc2[k][1].y + bb.w, 0.0f);
        mx0 = fmaxf(mx0, h0); mx1 = fmaxf(mx1, h1);
        mx2 = fmaxf(mx2, h2); mx3 = fmaxf(mx3, h3);
    }
    *(float4*)(f2 + q*C2_ + c0) = make_float4(mx0, mx1, mx2, mx3);
}

// ---------------------------------------------------------------- fused adaptive max+avg pool
__global__ __launch_bounds__(256) void pool_kernel(const float* __restrict__ f2,
                                                   float* __restrict__ out) {
    int bo = blockIdx.x;
    int b = bo / OUT_, o = bo % OUT_;
    int c = threadIdx.x;
    float mx = -3.4e38f, sm = 0.0f;
#pragma unroll
    for (int w = 0; w < M_/OUT_; ++w) {
        float v = f2[(b*M_ + o*(M_/OUT_) + w)*C2_ + c];
        mx = fmaxf(mx, v);
        sm += v;
    }
    out[(b*C2_ + c)*OUT_ + o] = mx + sm / (float)(M_/OUT_);
}

// ---------------------------------------------------------------- launch
extern "C" void kernel_launch(void* const* d_in, const int* in_sizes, int n_in,
                              void* d_out, int out_size, void* d_ws, size_t ws_size,
                              hipStream_t stream) {
    const float* x  = (const float*)d_in[0];
    const float* W1 = (const float*)d_in[1];
    const float* b1 = (const float*)d_in[2];
    const float* W2 = (const float*)d_in[3];
    const float* b2 = (const float*)d_in[4];
    float* out = (float*)d_out;

    char* ws = (char*)d_ws;
    size_t off = 0;
    auto alloc = [&](size_t bytes) {
        void* p = ws + off;
        off += (bytes + 255) & ~(size_t)255;
        return p;
    };
    float4* coords4 = (float4*)alloc((size_t)B_*N_*sizeof(float4));     // 2 MB
    float4* sub4    = (float4*)alloc((size_t)B_*SUBP_*sizeof(float4));  // 256 KB
    int*    idx2    = (int*)  alloc((size_t)B_*M_*K_*sizeof(int));      // 2 MB
    float*  f1      = (float*)alloc((size_t)B_*M_*C1_*sizeof(float));   // 8 MB
    float*  f2      = (float*)alloc((size_t)B_*M_*C2_*sizeof(float));   // 16 MB
    int*    progress= (int*)  alloc((size_t)B_*PSTRIDE_*sizeof(int));

    zero_kernel<<<1, 256, 0, stream>>>(progress);
    mega_kernel<<<B_ + NCB_, 512, 0, stream>>>(x, coords4, sub4, W1, b1, f1, progress);
    knn2_kernel<<<B_*M_/4, 256, 0, stream>>>(sub4, idx2);
    layer2_kernel<<<B_*M_, 64, 0, stream>>>(sub4, f1, idx2, W2, b2, f2);
    pool_kernel<<<B_*OUT_, 256, 0, stream>>>(f2, out);
}